// Round 8
// baseline (74.170 us; speedup 1.0000x reference)
//
#include <hip/hip_runtime.h>

#define NOUT1 12
#define NOUT2 15
#define NBINS 4000
#define NFEAT 6
#define NT    500
#define NTPAD 512
#define NEVT  64
#define LOG2E 1.4426950408889634f
#define LN2   0.6931471805599453f

typedef __attribute__((ext_vector_type(8))) short bf16x8;
typedef __attribute__((ext_vector_type(4))) float f32x4;
typedef __attribute__((ext_vector_type(2))) float f32x2;

__device__ __forceinline__ float leaky(float s) {
    return s >= 0.0f ? s : 0.01f * s;
}

__device__ __forceinline__ unsigned short f32_to_bf16_rne(float x) {
    unsigned int u = __float_as_uint(x);
    unsigned int r = (u + 0x7fffu + ((u >> 16) & 1u)) >> 16;
    return (unsigned short)r;
}
__device__ __forceinline__ float bf16_to_f32(unsigned short h) {
    return __uint_as_float((unsigned int)h << 16);
}

// d' = d*log2e (folded into W3/b3). softplus(d)/ln2 = max(d',0) + log2(1+2^-|d'|)
// Split accumulators: accm sums the max part, accp the cubic-minimax poly part.
__device__ __forceinline__ void sp2_acc2(f32x2 d, f32x2& accm, f32x2& accp) {
    accm += __builtin_elementwise_max(d, (f32x2)0.0f);
    f32x2 u;
    u.x = __builtin_amdgcn_exp2f(-__builtin_fabsf(d.x));
    u.y = __builtin_amdgcn_exp2f(-__builtin_fabsf(d.y));
    f32x2 q = __builtin_elementwise_fma(u, (f32x2)0.175167f, (f32x2)(-0.602758f));
    q = __builtin_elementwise_fma(u, q, (f32x2)1.428718f);
    accp = __builtin_elementwise_fma(u, q, accp);
}

// ---- one track's h2 hi/lo bf16 row (16 packed uints) ----
__device__ __forceinline__ void h2_row(
    const float* __restrict__ x, int e, int t,
    const float* __restrict__ W1, const float* __restrict__ b1,
    const float* __restrict__ W2, const float* __restrict__ b2,
    unsigned int packed[16])
{
    float f[NFEAT];
    #pragma unroll
    for (int i = 0; i < NFEAT; ++i)
        f[i] = x[e * NFEAT * NT + i * NT + t];   // x is (E, F, T)

    float h1[NOUT1];
    #pragma unroll
    for (int o = 0; o < NOUT1; ++o) {
        float s = b1[o];
        #pragma unroll
        for (int i = 0; i < NFEAT; ++i)
            s = fmaf(f[i], W1[o * NFEAT + i], s);
        h1[o] = leaky(s);
    }

    unsigned short hi[16], lo[16];
    #pragma unroll
    for (int o = 0; o < NOUT2; ++o) {
        float s = b2[o];
        #pragma unroll
        for (int i = 0; i < NOUT1; ++i)
            s = fmaf(h1[i], W2[o * NOUT1 + i], s);
        float h2 = leaky(s);
        unsigned short hh = f32_to_bf16_rne(h2);
        hi[o] = hh;
        lo[o] = f32_to_bf16_rne(h2 - bf16_to_f32(hh));
    }
    hi[15] = 0; lo[15] = 0;
    #pragma unroll
    for (int j = 0; j < 8; ++j) {
        packed[j]     = (unsigned int)hi[2*j] | ((unsigned int)hi[2*j+1] << 16);
        packed[8 + j] = (unsigned int)lo[2*j] | ((unsigned int)lo[2*j+1] << 16);
    }
}

// ---- Kernel 1: h2 prep -> ws in MFMA-direct order [e][tile32][kg4][col16] ----
__global__ __launch_bounds__(256) void h2_prep(
    const float* __restrict__ x,
    const float* __restrict__ W1, const float* __restrict__ b1,
    const float* __restrict__ W2, const float* __restrict__ b2,
    uint4* __restrict__ ws)
{
    const int e = blockIdx.x;
    const int t = blockIdx.y * 256 + threadIdx.x;
    unsigned int packed[16];
    if (t < NT) {
        h2_row(x, e, t, W1, b1, W2, b2, packed);
    } else {
        #pragma unroll
        for (int j = 0; j < 16; ++j) packed[j] = 0;
    }
    uint4* dst = ws + (size_t)e * 2048 + (t >> 4) * 64 + (t & 15);
    #pragma unroll
    for (int g = 0; g < 4; ++g)
        dst[g * 16] = make_uint4(packed[4*g+0], packed[4*g+1], packed[4*g+2], packed[4*g+3]);
}

// ---- Phase 2 body: 16 bins x 512 tracks per wave via MFMA ----
__device__ __forceinline__ void kde_phase2(
    const uint4* __restrict__ h2lds,   // [tile32][kg4][col16]
    const float* __restrict__ W3, const float* __restrict__ b3,
    float* __restrict__ out, int chunk, int e, int tid)
{
    const int wid  = tid >> 6;
    const int lane = tid & 63;
    const int col  = lane & 15;
    const int kg   = lane >> 4;
    const int binbase = chunk * 256 + wid * 16;
    if (binbase >= NBINS) return;              // wave-uniform
    const int  bin = binbase + col;
    const bool vb  = (bin < NBINS);

    // W3 row for this lane's bin: 12 via float4 (4B-aligned ok), 3 scalar
    float wrow[NOUT2];
    {
        const float* wp = &W3[(vb ? bin : 0) * NOUT2];
        #pragma unroll
        for (int g = 0; g < 3; ++g) {
            float4 v = *reinterpret_cast<const float4*>(wp + g * 4);
            wrow[g*4+0] = v.x; wrow[g*4+1] = v.y; wrow[g*4+2] = v.z; wrow[g*4+3] = v.w;
        }
        wrow[12] = wp[12]; wrow[13] = wp[13]; wrow[14] = wp[14];
    }

    // B frags (weights pre-scaled by log2e): B1 = [w_hi | w_lo], B2 swapped
    bf16x8 B1, B2;
    const bool hi_first = (kg < 2);
    #pragma unroll
    for (int j = 0; j < 8; ++j) {
        const int kk = (kg * 8 + j) & 15;
        float w = (vb && kk < NOUT2) ? wrow[kk < NOUT2 ? kk : 0] * LOG2E : 0.0f;
        unsigned short h = f32_to_bf16_rne(w);
        unsigned short l = f32_to_bf16_rne(w - bf16_to_f32(h));
        B1[j] = (short)(hi_first ? h : l);
        B2[j] = (short)(hi_first ? l : h);
    }

    const float bias = vb ? b3[bin] * LOG2E : 0.0f;
    f32x4 bias4 = {bias, bias, bias, bias};

    f32x2 m0 = {0.f,0.f}, m1 = m0, m2 = m0, m3 = m0;
    f32x2 p0 = m0, p1 = m0, p2 = m0, p3 = m0;
    const bf16x8* ap = reinterpret_cast<const bf16x8*>(h2lds + kg * 16 + col);

    // 8 batches x 4 tiles: 4 named A-frags, 4 independent MFMA chains,
    // 8 independent softplus acc chains — static ILP for the scheduler.
    #pragma unroll
    for (int b = 0; b < 8; ++b) {
        bf16x8 a0 = ap[(4*b + 0) * 64];
        bf16x8 a1 = ap[(4*b + 1) * 64];
        bf16x8 a2 = ap[(4*b + 2) * 64];
        bf16x8 a3 = ap[(4*b + 3) * 64];

        f32x4 c0 = __builtin_amdgcn_mfma_f32_16x16x32_bf16(a0, B1, bias4, 0, 0, 0);
        f32x4 c1 = __builtin_amdgcn_mfma_f32_16x16x32_bf16(a1, B1, bias4, 0, 0, 0);
        f32x4 c2 = __builtin_amdgcn_mfma_f32_16x16x32_bf16(a2, B1, bias4, 0, 0, 0);
        f32x4 c3 = __builtin_amdgcn_mfma_f32_16x16x32_bf16(a3, B1, bias4, 0, 0, 0);
        c0 = __builtin_amdgcn_mfma_f32_16x16x32_bf16(a0, B2, c0, 0, 0, 0);
        c1 = __builtin_amdgcn_mfma_f32_16x16x32_bf16(a1, B2, c1, 0, 0, 0);
        c2 = __builtin_amdgcn_mfma_f32_16x16x32_bf16(a2, B2, c2, 0, 0, 0);
        c3 = __builtin_amdgcn_mfma_f32_16x16x32_bf16(a3, B2, c3, 0, 0, 0);

        f32x2 d;
        d.x = c0[0]; d.y = c0[1]; sp2_acc2(d, m0, p0);
        d.x = c0[2]; d.y = c0[3]; sp2_acc2(d, m0, p0);
        d.x = c1[0]; d.y = c1[1]; sp2_acc2(d, m1, p1);
        d.x = c1[2]; d.y = c1[3]; sp2_acc2(d, m1, p1);
        d.x = c2[0]; d.y = c2[1]; sp2_acc2(d, m2, p2);
        d.x = c2[2]; d.y = c2[3]; sp2_acc2(d, m2, p2);
        if (b < 7) {
            d.x = c3[0]; d.y = c3[1]; sp2_acc2(d, m3, p3);
            d.x = c3[2]; d.y = c3[3]; sp2_acc2(d, m3, p3);
        } else if (kg == 0) {
            // tile 31: tracks 496..511; only kg==0 rows (496..499) are real
            d.x = c3[0]; d.y = c3[1]; sp2_acc2(d, m3, p3);
            d.x = c3[2]; d.y = c3[3]; sp2_acc2(d, m3, p3);
        }
    }

    f32x2 s2 = (m0 + m1) + (m2 + m3) + (p0 + p1) + (p2 + p3);
    float sum = s2.x + s2.y;
    sum += __shfl_xor(sum, 16);
    sum += __shfl_xor(sum, 32);
    if (lane < 16 && vb)
        out[e * NBINS + bin] = sum * LN2;      // undo log2 scaling once
}

// ---- Kernel 2: stage ws -> LDS (identity copy), then MFMA + softplus ----
__global__ __launch_bounds__(1024, 4) void kde_main(
    const uint4* __restrict__ ws,
    const float* __restrict__ W3, const float* __restrict__ b3,
    float* __restrict__ out)
{
    __shared__ uint4 h2lds[2048];   // 32 KB, [tile32][kg4][col16]
    const int tid   = threadIdx.x;
    const int chunk = blockIdx.x;
    const int e     = blockIdx.y;

    h2lds[tid]        = ws[(size_t)e * 2048 + tid];
    h2lds[tid + 1024] = ws[(size_t)e * 2048 + tid + 1024];
    __syncthreads();

    kde_phase2(h2lds, W3, b3, out, chunk, e, tid);
}

// ---- Fallback: fused single kernel (if ws too small) ----
__global__ __launch_bounds__(1024, 2) void kde_fused(
    const float* __restrict__ x,
    const float* __restrict__ W1, const float* __restrict__ b1,
    const float* __restrict__ W2, const float* __restrict__ b2,
    const float* __restrict__ W3, const float* __restrict__ b3,
    float* __restrict__ out)
{
    __shared__ uint4 h2lds[2048];
    const int tid   = threadIdx.x;
    const int chunk = blockIdx.x;
    const int e     = blockIdx.y;

    if (tid < NTPAD) {
        unsigned int packed[16];
        if (tid < NT) {
            h2_row(x, e, tid, W1, b1, W2, b2, packed);
        } else {
            #pragma unroll
            for (int j = 0; j < 16; ++j) packed[j] = 0;
        }
        uint4* dst = &h2lds[(tid >> 4) * 64 + (tid & 15)];
        #pragma unroll
        for (int g = 0; g < 4; ++g)
            dst[g * 16] = make_uint4(packed[4*g+0], packed[4*g+1], packed[4*g+2], packed[4*g+3]);
    }
    __syncthreads();

    kde_phase2(h2lds, W3, b3, out, chunk, e, tid);
}

extern "C" void kernel_launch(void* const* d_in, const int* in_sizes, int n_in,
                              void* d_out, int out_size, void* d_ws, size_t ws_size,
                              hipStream_t stream) {
    const float* x  = (const float*)d_in[0];
    const float* W1 = (const float*)d_in[1];
    const float* b1 = (const float*)d_in[2];
    const float* W2 = (const float*)d_in[3];
    const float* b2 = (const float*)d_in[4];
    const float* W3 = (const float*)d_in[5];
    const float* b3 = (const float*)d_in[6];
    float* out = (float*)d_out;

    const size_t ws_needed = (size_t)NEVT * 2048 * sizeof(uint4);   // 2 MB
    if (ws_size >= ws_needed) {
        dim3 pgrid(NEVT, 2);
        h2_prep<<<pgrid, 256, 0, stream>>>(x, W1, b1, W2, b2, (uint4*)d_ws);
        dim3 grid(16, NEVT);
        kde_main<<<grid, 1024, 0, stream>>>((const uint4*)d_ws, W3, b3, out);
    } else {
        dim3 grid(16, NEVT);
        kde_fused<<<grid, 1024, 0, stream>>>(x, W1, b1, W2, b2, W3, b3, out);
    }
}

// Round 9
// 45.121 us; speedup vs baseline: 1.6438x; 1.6438x over previous
//
#include <hip/hip_runtime.h>

#define NOUT1 12
#define NOUT2 15
#define NBINS 4000
#define NFEAT 6
#define NT    500
#define NTPAD 512
#define NEVT  64
#define LOG2E 1.4426950408889634f
#define LN2   0.6931471805599453f

typedef __attribute__((ext_vector_type(8))) short bf16x8;
typedef __attribute__((ext_vector_type(4))) float f32x4;
typedef __attribute__((ext_vector_type(2))) float f32x2;

__device__ __forceinline__ float leaky(float s) {
    return s >= 0.0f ? s : 0.01f * s;
}

__device__ __forceinline__ unsigned short f32_to_bf16_rne(float x) {
    unsigned int u = __float_as_uint(x);
    unsigned int r = (u + 0x7fffu + ((u >> 16) & 1u)) >> 16;
    return (unsigned short)r;
}
__device__ __forceinline__ float bf16_to_f32(unsigned short h) {
    return __uint_as_float((unsigned int)h << 16);
}

// d' = d * log2e (scale folded into W3/b3).
// softplus(d)/ln2 = max(d',0) + log2(1 + 2^(-|d'|)); cubic minimax,
// |abs err| ~= 1.2e-3 (in ln units). exp2(-|x|) is ONE v_exp_f32.
__device__ __forceinline__ void sp2_acc(f32x2 d, f32x2& acc) {
    f32x2 u;
    u.x = __builtin_amdgcn_exp2f(-__builtin_fabsf(d.x));
    u.y = __builtin_amdgcn_exp2f(-__builtin_fabsf(d.y));
    acc += __builtin_elementwise_max(d, (f32x2)0.0f);
    f32x2 q = __builtin_elementwise_fma(u, (f32x2)0.175167f, (f32x2)(-0.602758f));
    q = __builtin_elementwise_fma(u, q, (f32x2)1.428718f);
    acc = __builtin_elementwise_fma(u, q, acc);
}

// ---- one track's h2 hi/lo bf16 row (16 packed uints) ----
__device__ __forceinline__ void h2_row(
    const float* __restrict__ x, int e, int t,
    const float* __restrict__ W1, const float* __restrict__ b1,
    const float* __restrict__ W2, const float* __restrict__ b2,
    unsigned int packed[16])
{
    float f[NFEAT];
    #pragma unroll
    for (int i = 0; i < NFEAT; ++i)
        f[i] = x[e * NFEAT * NT + i * NT + t];   // x is (E, F, T)

    float h1[NOUT1];
    #pragma unroll
    for (int o = 0; o < NOUT1; ++o) {
        float s = b1[o];
        #pragma unroll
        for (int i = 0; i < NFEAT; ++i)
            s = fmaf(f[i], W1[o * NFEAT + i], s);
        h1[o] = leaky(s);
    }

    unsigned short hi[16], lo[16];
    #pragma unroll
    for (int o = 0; o < NOUT2; ++o) {
        float s = b2[o];
        #pragma unroll
        for (int i = 0; i < NOUT1; ++i)
            s = fmaf(h1[i], W2[o * NOUT1 + i], s);
        float h2 = leaky(s);
        unsigned short hh = f32_to_bf16_rne(h2);
        hi[o] = hh;
        lo[o] = f32_to_bf16_rne(h2 - bf16_to_f32(hh));
    }
    hi[15] = 0; lo[15] = 0;
    #pragma unroll
    for (int j = 0; j < 8; ++j) {
        packed[j]     = (unsigned int)hi[2*j] | ((unsigned int)hi[2*j+1] << 16);
        packed[8 + j] = (unsigned int)lo[2*j] | ((unsigned int)lo[2*j+1] << 16);
    }
}

// ---- Kernel 1: h2 prep -> ws in MFMA-direct order [e][tile32][kg4][col16] ----
__global__ __launch_bounds__(256) void h2_prep(
    const float* __restrict__ x,
    const float* __restrict__ W1, const float* __restrict__ b1,
    const float* __restrict__ W2, const float* __restrict__ b2,
    uint4* __restrict__ ws)
{
    const int e = blockIdx.x;
    const int t = blockIdx.y * 256 + threadIdx.x;
    unsigned int packed[16];
    if (t < NT) {
        h2_row(x, e, t, W1, b1, W2, b2, packed);
    } else {
        #pragma unroll
        for (int j = 0; j < 16; ++j) packed[j] = 0;
    }
    uint4* dst = ws + (size_t)e * 2048 + (t >> 4) * 64 + (t & 15);
    #pragma unroll
    for (int g = 0; g < 4; ++g)
        dst[g * 16] = make_uint4(packed[4*g+0], packed[4*g+1], packed[4*g+2], packed[4*g+3]);
}

// ---- Phase 2 body: 16 bins x 512 tracks per wave via MFMA ----
// (byte-identical compute to the R6 41.5us version; only binbase scale differs)
__device__ __forceinline__ void kde_phase2(
    const uint4* __restrict__ h2lds,   // [tile32][kg4][col16]
    const float* __restrict__ W3, const float* __restrict__ b3,
    float* __restrict__ out, int chunk, int e, int tid)
{
    const int wid  = tid >> 6;
    const int lane = tid & 63;
    const int col  = lane & 15;
    const int kg   = lane >> 4;
    const int binbase = chunk * 128 + wid * 16;   // 512-thread block = 8 waves = 128 bins
    if (binbase >= NBINS) return;              // wave-uniform
    const int  bin = binbase + col;
    const bool vb  = (bin < NBINS);

    // B frags (weights pre-scaled by log2e): B1 = [w_hi | w_lo], B2 swapped
    bf16x8 B1, B2;
    const bool hi_first = (kg < 2);
    #pragma unroll
    for (int j = 0; j < 8; ++j) {
        const int kk = (kg * 8 + j) & 15;
        float w = (vb && kk < NOUT2) ? W3[bin * NOUT2 + kk] * LOG2E : 0.0f;
        unsigned short h = f32_to_bf16_rne(w);
        unsigned short l = f32_to_bf16_rne(w - bf16_to_f32(h));
        B1[j] = (short)(hi_first ? h : l);
        B2[j] = (short)(hi_first ? l : h);
    }

    const float bias = vb ? b3[bin] * LOG2E : 0.0f;
    f32x4 bias4 = {bias, bias, bias, bias};

    f32x2 acc01 = {0.0f, 0.0f}, acc23 = {0.0f, 0.0f};
    const bf16x8* ap = reinterpret_cast<const bf16x8*>(h2lds + kg * 16 + col);

    #define TILE_BODY(areg)                                                        \
        {                                                                          \
            f32x4 acc = __builtin_amdgcn_mfma_f32_16x16x32_bf16(areg, B1, bias4, 0, 0, 0); \
            acc = __builtin_amdgcn_mfma_f32_16x16x32_bf16(areg, B2, acc, 0, 0, 0); \
            f32x2 p01 = {acc[0], acc[1]};                                          \
            f32x2 p23 = {acc[2], acc[3]};                                          \
            sp2_acc(p01, acc01);                                                   \
            sp2_acc(p23, acc23);                                                   \
        }

    // distance-4 LDS prefetch ring; full unroll keeps all indices static
    bf16x8 A[4];
    A[0] = ap[0 * 64];
    A[1] = ap[1 * 64];
    A[2] = ap[2 * 64];
    A[3] = ap[3 * 64];

    #pragma unroll
    for (int g = 0; g < 31; ++g) {
        bf16x8 cur = A[g & 3];
        if (g + 4 < 32)
            A[g & 3] = ap[(g + 4) * 64];   // issue next ds_read before compute
        TILE_BODY(cur)
    }
    {   // tile 31: tracks 496..511; only kg==0 rows (tracks 496..499) are real
        bf16x8 cur = A[31 & 3];
        f32x4 acc = __builtin_amdgcn_mfma_f32_16x16x32_bf16(cur, B1, bias4, 0, 0, 0);
        acc = __builtin_amdgcn_mfma_f32_16x16x32_bf16(cur, B2, acc, 0, 0, 0);
        if (kg == 0) {
            f32x2 p01 = {acc[0], acc[1]};
            f32x2 p23 = {acc[2], acc[3]};
            sp2_acc(p01, acc01);
            sp2_acc(p23, acc23);
        }
    }
    #undef TILE_BODY

    float sum = acc01.x + acc01.y + acc23.x + acc23.y;
    sum += __shfl_xor(sum, 16);
    sum += __shfl_xor(sum, 32);
    if (lane < 16 && vb)
        out[e * NBINS + bin] = sum * LN2;      // undo log2 scaling once
}

// ---- Kernel 2: stage ws -> LDS, then MFMA + softplus ----
// 512-thread blocks: 4 blocks/CU (128KB LDS, 2048 thr) = 8 waves/SIMD
__global__ __launch_bounds__(512, 8) void kde_main(
    const uint4* __restrict__ ws,
    const float* __restrict__ W3, const float* __restrict__ b3,
    float* __restrict__ out)
{
    __shared__ uint4 h2lds[2048];   // 32 KB, [tile32][kg4][col16]
    const int tid   = threadIdx.x;
    const int chunk = blockIdx.x;   // 0..31 -> 128 bins each
    const int e     = blockIdx.y;

    #pragma unroll
    for (int k = 0; k < 4; ++k)
        h2lds[tid + k * 512] = ws[(size_t)e * 2048 + tid + k * 512];
    __syncthreads();

    kde_phase2(h2lds, W3, b3, out, chunk, e, tid);
}

// ---- Fallback: fused single kernel (if ws too small) ----
__global__ __launch_bounds__(512, 2) void kde_fused(
    const float* __restrict__ x,
    const float* __restrict__ W1, const float* __restrict__ b1,
    const float* __restrict__ W2, const float* __restrict__ b2,
    const float* __restrict__ W3, const float* __restrict__ b3,
    float* __restrict__ out)
{
    __shared__ uint4 h2lds[2048];
    const int tid   = threadIdx.x;
    const int chunk = blockIdx.x;
    const int e     = blockIdx.y;

    {
        unsigned int packed[16];
        if (tid < NT) {
            h2_row(x, e, tid, W1, b1, W2, b2, packed);
        } else {
            #pragma unroll
            for (int j = 0; j < 16; ++j) packed[j] = 0;
        }
        uint4* dst = &h2lds[(tid >> 4) * 64 + (tid & 15)];
        #pragma unroll
        for (int g = 0; g < 4; ++g)
            dst[g * 16] = make_uint4(packed[4*g+0], packed[4*g+1], packed[4*g+2], packed[4*g+3]);
    }
    __syncthreads();

    kde_phase2(h2lds, W3, b3, out, chunk, e, tid);
}

extern "C" void kernel_launch(void* const* d_in, const int* in_sizes, int n_in,
                              void* d_out, int out_size, void* d_ws, size_t ws_size,
                              hipStream_t stream) {
    const float* x  = (const float*)d_in[0];
    const float* W1 = (const float*)d_in[1];
    const float* b1 = (const float*)d_in[2];
    const float* W2 = (const float*)d_in[3];
    const float* b2 = (const float*)d_in[4];
    const float* W3 = (const float*)d_in[5];
    const float* b3 = (const float*)d_in[6];
    float* out = (float*)d_out;

    const size_t ws_needed = (size_t)NEVT * 2048 * sizeof(uint4);   // 2 MB
    if (ws_size >= ws_needed) {
        dim3 pgrid(NEVT, 2);
        h2_prep<<<pgrid, 256, 0, stream>>>(x, W1, b1, W2, b2, (uint4*)d_ws);
        dim3 grid(32, NEVT);
        kde_main<<<grid, 512, 0, stream>>>((const uint4*)d_ws, W3, b3, out);
    } else {
        dim3 grid(32, NEVT);
        kde_fused<<<grid, 512, 0, stream>>>(x, W1, b1, W2, b2, W3, b3, out);
    }
}

// Round 11
// 37.917 us; speedup vs baseline: 1.9561x; 1.1900x over previous
//
#include <hip/hip_runtime.h>

#define NOUT1 12
#define NOUT2 15
#define NBINS 4000
#define NFEAT 6
#define NT    500
#define NTPAD 512
#define NEVT  64
#define LOG2E 1.4426950408889634f
#define LN2   0.6931471805599453f

typedef __attribute__((ext_vector_type(4))) _Float16 f16x4;
typedef __attribute__((ext_vector_type(4))) float f32x4;
typedef __attribute__((ext_vector_type(2))) float f32x2;

__device__ __forceinline__ float leaky(float s) {
    return s >= 0.0f ? s : 0.01f * s;
}

// d' = d*log2e (scale folded into W3/b3 upstream).
// softplus(d)/ln2 = max(d',0) + log2(1+2^(-|d'|)); cubic minimax, |err|~1.2e-3 ln.
__device__ __forceinline__ void sp2_acc(f32x2 d, f32x2& acc) {
    f32x2 u;
    u.x = __builtin_amdgcn_exp2f(-__builtin_fabsf(d.x));
    u.y = __builtin_amdgcn_exp2f(-__builtin_fabsf(d.y));
    acc += __builtin_elementwise_max(d, (f32x2)0.0f);
    f32x2 q = __builtin_elementwise_fma(u, (f32x2)0.175167f, (f32x2)(-0.602758f));
    q = __builtin_elementwise_fma(u, q, (f32x2)1.428718f);
    acc = __builtin_elementwise_fma(u, q, acc);
}

__device__ __forceinline__ unsigned short f16bits(float v) {
    return __builtin_bit_cast(unsigned short, (_Float16)v);
}

// ---- one track's h2 row as 16 f16 (slot15 = 1.0 bias carrier) ----
__device__ __forceinline__ void h2_row_f16(
    const float* __restrict__ x, int e, int t,
    const float* __restrict__ W1, const float* __restrict__ b1,
    const float* __restrict__ W2, const float* __restrict__ b2,
    unsigned int packed[8])
{
    float f[NFEAT];
    #pragma unroll
    for (int i = 0; i < NFEAT; ++i)
        f[i] = x[e * NFEAT * NT + i * NT + t];   // x is (E, F, T)

    float h1[NOUT1];
    #pragma unroll
    for (int o = 0; o < NOUT1; ++o) {
        float s = b1[o];
        #pragma unroll
        for (int i = 0; i < NFEAT; ++i)
            s = fmaf(f[i], W1[o * NFEAT + i], s);
        h1[o] = leaky(s);
    }

    unsigned short hf[16];
    #pragma unroll
    for (int o = 0; o < NOUT2; ++o) {
        float s = b2[o];
        #pragma unroll
        for (int i = 0; i < NOUT1; ++i)
            s = fmaf(h1[i], W2[o * NOUT1 + i], s);
        hf[o] = f16bits(leaky(s));
    }
    hf[15] = f16bits(1.0f);   // bias carrier slot
    #pragma unroll
    for (int j = 0; j < 8; ++j)
        packed[j] = (unsigned int)hf[2*j] | ((unsigned int)hf[2*j+1] << 16);
}

// ---- Kernel 1a: h2 prep -> wsA in MFMA-direct order [e][tile32][kg4][col16] (uint2) ----
__global__ __launch_bounds__(256) void h2_prep(
    const float* __restrict__ x,
    const float* __restrict__ W1, const float* __restrict__ b1,
    const float* __restrict__ W2, const float* __restrict__ b2,
    uint2* __restrict__ wsA)
{
    const int e = blockIdx.x;
    const int t = blockIdx.y * 256 + threadIdx.x;
    unsigned int packed[8];
    if (t < NT) {
        h2_row_f16(x, e, t, W1, b1, W2, b2, packed);
    } else {
        #pragma unroll
        for (int j = 0; j < 8; ++j) packed[j] = 0;   // pad rows fully zero
    }
    uint2* dst = wsA + (size_t)e * 2048 + (t >> 4) * 64 + (t & 15);
    dst[0]  = make_uint2(packed[0], packed[1]);
    dst[16] = make_uint2(packed[2], packed[3]);
    dst[32] = make_uint2(packed[4], packed[5]);
    dst[48] = make_uint2(packed[6], packed[7]);
}

// ---- Kernel 1b: W3 prep -> wsB[bin][16 f16] = W3*log2e, slot15 = b3*log2e ----
__global__ __launch_bounds__(256) void w3_prep(
    const float* __restrict__ W3, const float* __restrict__ b3,
    uint2* __restrict__ wsB)
{
    const int bin = blockIdx.x * 256 + threadIdx.x;
    if (bin >= NBINS) return;
    unsigned short wf[16];
    #pragma unroll
    for (int k = 0; k < NOUT2; ++k)
        wf[k] = f16bits(W3[bin * NOUT2 + k] * LOG2E);
    wf[15] = f16bits(b3[bin] * LOG2E);
    uint2* dst = wsB + (size_t)bin * 4;
    #pragma unroll
    for (int g = 0; g < 4; ++g)
        dst[g] = make_uint2((unsigned int)wf[4*g] | ((unsigned int)wf[4*g+1] << 16),
                            (unsigned int)wf[4*g+2] | ((unsigned int)wf[4*g+3] << 16));
}

// ---- Phase 2 body: 16 bins x 512 tracks per wave, one 16x16x16 f16 MFMA/tile ----
__device__ __forceinline__ void kde_phase2(
    const uint2* __restrict__ h2lds,   // [tile32][kg4][col16] uint2 (f16x4)
    f16x4 B1, float* __restrict__ out, int binbase, int e, int lane)
{
    const int col = lane & 15;
    const int kg  = lane >> 4;
    const int bin = binbase + col;

    const f32x4 zero4 = {0.0f, 0.0f, 0.0f, 0.0f};
    f32x2 acc01 = {0.0f, 0.0f}, acc23 = {0.0f, 0.0f};
    const uint2* ap = h2lds + kg * 16 + col;

    #define TILE_BODY(areg)                                                        \
        {                                                                          \
            f16x4 av = __builtin_bit_cast(f16x4, areg);                            \
            f32x4 c = __builtin_amdgcn_mfma_f32_16x16x16f16(av, B1, zero4, 0, 0, 0); \
            f32x2 p01 = {c[0], c[1]};                                              \
            f32x2 p23 = {c[2], c[3]};                                              \
            sp2_acc(p01, acc01);                                                   \
            sp2_acc(p23, acc23);                                                   \
        }

    // distance-4 LDS prefetch ring; full unroll keeps all indices static
    uint2 A[4];
    A[0] = ap[0 * 64];
    A[1] = ap[1 * 64];
    A[2] = ap[2 * 64];
    A[3] = ap[3 * 64];

    #pragma unroll
    for (int g = 0; g < 31; ++g) {
        uint2 cur = A[g & 3];
        if (g + 4 < 32)
            A[g & 3] = ap[(g + 4) * 64];
        TILE_BODY(cur)
    }
    {   // tile 31: tracks 496..511; C row = kg*4+reg -> only kg==0 (496..499) real
        f16x4 av = __builtin_bit_cast(f16x4, A[3]);
        f32x4 c = __builtin_amdgcn_mfma_f32_16x16x16f16(av, B1, zero4, 0, 0, 0);
        if (kg == 0) {
            f32x2 p01 = {c[0], c[1]};
            f32x2 p23 = {c[2], c[3]};
            sp2_acc(p01, acc01);
            sp2_acc(p23, acc23);
        }
    }
    #undef TILE_BODY

    f32x2 s2 = acc01 + acc23;
    float sum = s2.x + s2.y;
    sum += __shfl_xor(sum, 16);
    sum += __shfl_xor(sum, 32);
    if (lane < 16 && bin < NBINS)
        out[e * NBINS + bin] = sum * LN2;
}

// ---- Kernel 2: stage wsA -> LDS (identity copy), load B-frag, compute ----
__global__ __launch_bounds__(512, 8) void kde_main(
    const uint2* __restrict__ wsA, const uint2* __restrict__ wsB,
    float* __restrict__ out)
{
    __shared__ uint2 h2lds[2048];   // 16 KB, [tile32][kg4][col16]
    const int tid   = threadIdx.x;
    const int chunk = blockIdx.x;   // 0..31 -> 128 bins each
    const int e     = blockIdx.y;

    {   // 16 KB identity copy, uint4-wide
        uint4* l4 = reinterpret_cast<uint4*>(h2lds);
        const uint4* g4 = reinterpret_cast<const uint4*>(wsA + (size_t)e * 2048);
        l4[tid]       = g4[tid];
        l4[tid + 512] = g4[tid + 512];
    }

    const int wid  = tid >> 6;
    const int lane = tid & 63;
    const int binbase = chunk * 128 + wid * 16;
    const int col = lane & 15;
    const int kg  = lane >> 4;
    const int binc = (binbase + col < NBINS) ? binbase + col : NBINS - 1;
    // B fragment: one 8B load from precomputed table (L2-resident, 128 KB)
    f16x4 B1 = __builtin_bit_cast(f16x4, wsB[(size_t)binc * 4 + kg]);

    __syncthreads();
    if (binbase >= NBINS) return;   // wave-uniform

    kde_phase2(h2lds, B1, out, binbase, e, lane);
}

// ---- Fallback: fused single kernel (if ws too small) ----
__global__ __launch_bounds__(512, 2) void kde_fused(
    const float* __restrict__ x,
    const float* __restrict__ W1, const float* __restrict__ b1,
    const float* __restrict__ W2, const float* __restrict__ b2,
    const float* __restrict__ W3, const float* __restrict__ b3,
    float* __restrict__ out)
{
    __shared__ uint2 h2lds[2048];
    const int tid   = threadIdx.x;
    const int chunk = blockIdx.x;
    const int e     = blockIdx.y;

    {
        unsigned int packed[8];
        if (tid < NT) {
            h2_row_f16(x, e, tid, W1, b1, W2, b2, packed);
        } else {
            #pragma unroll
            for (int j = 0; j < 8; ++j) packed[j] = 0;
        }
        uint2* dst = &h2lds[(tid >> 4) * 64 + (tid & 15)];
        dst[0]  = make_uint2(packed[0], packed[1]);
        dst[16] = make_uint2(packed[2], packed[3]);
        dst[32] = make_uint2(packed[4], packed[5]);
        dst[48] = make_uint2(packed[6], packed[7]);
    }

    const int wid  = tid >> 6;
    const int lane = tid & 63;
    const int binbase = chunk * 128 + wid * 16;
    const int col = lane & 15;
    const int kg  = lane >> 4;
    const int binc = (binbase + col < NBINS) ? binbase + col : NBINS - 1;
    f16x4 B1;
    #pragma unroll
    for (int j = 0; j < 4; ++j) {
        const int kk = kg * 4 + j;
        float w = (kk < NOUT2) ? W3[binc * NOUT2 + kk] * LOG2E
                               : b3[binc] * LOG2E;     // kk==15 -> bias slot
        B1[j] = (_Float16)w;
    }

    __syncthreads();
    if (binbase >= NBINS) return;

    kde_phase2(h2lds, B1, out, binbase, e, lane);
}

extern "C" void kernel_launch(void* const* d_in, const int* in_sizes, int n_in,
                              void* d_out, int out_size, void* d_ws, size_t ws_size,
                              hipStream_t stream) {
    const float* x  = (const float*)d_in[0];
    const float* W1 = (const float*)d_in[1];
    const float* b1 = (const float*)d_in[2];
    const float* W2 = (const float*)d_in[3];
    const float* b2 = (const float*)d_in[4];
    const float* W3 = (const float*)d_in[5];
    const float* b3 = (const float*)d_in[6];
    float* out = (float*)d_out;

    // ws layout: wsA = 64 events x 16 KB (1 MB); wsB = 4000 x 32 B (128 KB)
    const size_t wsA_bytes = (size_t)NEVT * 2048 * sizeof(uint2);
    const size_t wsB_bytes = (size_t)NBINS * 4 * sizeof(uint2);
    if (ws_size >= wsA_bytes + wsB_bytes) {
        uint2* wsA = (uint2*)d_ws;
        uint2* wsB = (uint2*)((char*)d_ws + wsA_bytes);
        dim3 pgrid(NEVT, 2);
        h2_prep<<<pgrid, 256, 0, stream>>>(x, W1, b1, W2, b2, wsA);
        w3_prep<<<16, 256, 0, stream>>>(W3, b3, wsB);
        dim3 grid(32, NEVT);
        kde_main<<<grid, 512, 0, stream>>>(wsA, wsB, out);
    } else {
        dim3 grid(32, NEVT);
        kde_fused<<<grid, 512, 0, stream>>>(x, W1, b1, W2, b2, W3, b3, out);
    }
}